// Round 1
// baseline (1637.776 us; speedup 1.0000x reference)
//
#include <hip/hip_runtime.h>
#include <cstdint>
#include <cmath>

// Problem constants (B=4, S=2048, H=2048, I=4096, E=8, K=2)
#define T_TOK 8192     // B*S
#define H_DIM 2048
#define I_DIM 4096
#define E_NUM 8
#define NROWS 16384    // T*K

typedef __bf16 bf16x8 __attribute__((ext_vector_type(8)));
typedef float f32x4 __attribute__((ext_vector_type(4)));

__device__ __forceinline__ uint16_t f2bf(float f) {
  union { float f; uint32_t u; } v; v.f = f;
  uint32_t u = v.u;
  uint32_t r = (u + 0x7fffu + ((u >> 16) & 1u)) >> 16;
  return (uint16_t)r;
}
__device__ __forceinline__ float bf2f(uint32_t b) {
  union { uint32_t u; float f; } v; v.u = b << 16;
  return v.f;
}

__device__ __forceinline__ float gelu_tanh(float x) {
  float u = 0.7978845608028654f * (x + 0.044715f * x * x * x);
  return 0.5f * x * (1.0f + tanhf(u));
}

// ---------------- router: logits -> softmax -> top-2, histogram ----------------
__global__ __launch_bounds__(256) void router_kernel(
    const float* __restrict__ x, const float* __restrict__ rw,
    int* __restrict__ expert_idx, float* __restrict__ expert_w,
    int* __restrict__ counts) {
  int t = blockIdx.x * 4 + (threadIdx.x >> 6);   // one wave per token
  int lane = threadIdx.x & 63;
  const float* xr = x + (size_t)t * H_DIM;
  float acc[E_NUM];
#pragma unroll
  for (int e = 0; e < E_NUM; ++e) acc[e] = 0.f;
  for (int j = 0; j < H_DIM / 64; ++j) {
    float xv = xr[lane + 64 * j];
#pragma unroll
    for (int e = 0; e < E_NUM; ++e) acc[e] += xv * rw[e * H_DIM + lane + 64 * j];
  }
#pragma unroll
  for (int e = 0; e < E_NUM; ++e) {
#pragma unroll
    for (int off = 32; off > 0; off >>= 1) acc[e] += __shfl_xor(acc[e], off);
  }
  if (lane == 0) {
    float mx = acc[0];
#pragma unroll
    for (int e = 1; e < E_NUM; ++e) mx = fmaxf(mx, acc[e]);
    float s[E_NUM]; float sum = 0.f;
#pragma unroll
    for (int e = 0; e < E_NUM; ++e) { s[e] = __expf(acc[e] - mx); sum += s[e]; }
    float inv = 1.f / sum;
#pragma unroll
    for (int e = 0; e < E_NUM; ++e) s[e] *= inv;
    int i0 = 0; float w0 = s[0];
#pragma unroll
    for (int e = 1; e < E_NUM; ++e) if (s[e] > w0) { w0 = s[e]; i0 = e; }
    s[i0] = -1.f;
    int i1 = 0; float w1 = s[0];
#pragma unroll
    for (int e = 1; e < E_NUM; ++e) if (s[e] > w1) { w1 = s[e]; i1 = e; }
    expert_idx[2 * t] = i0; expert_idx[2 * t + 1] = i1;
    expert_w[2 * t] = w0;  expert_w[2 * t + 1] = w1;
    atomicAdd(&counts[i0], 1);
    atomicAdd(&counts[i1], 1);
  }
}

// ---------------- plan: offsets + ragged tile metadata (256-row tiles) ----------------
__global__ void plan_kernel(const int* __restrict__ counts, int* __restrict__ offsets,
                            int* __restrict__ tile_meta, int* __restrict__ ntilesp,
                            float* __restrict__ out_counts) {
  if (threadIdx.x == 0 && blockIdx.x == 0) {
    int off = 0, nt = 0;
    for (int e = 0; e < E_NUM; ++e) {
      int cnt = counts[e];
      offsets[e] = off;
      out_counts[e] = (float)cnt;
      int ntile = (cnt + 255) >> 8;
      for (int i = 0; i < ntile; ++i) {
        int rem = cnt - i * 256;
        tile_meta[nt * 4 + 0] = off + i * 256;
        tile_meta[nt * 4 + 1] = rem < 256 ? rem : 256;
        tile_meta[nt * 4 + 2] = e;
        ++nt;
      }
      off += cnt;
    }
    *ntilesp = nt;
  }
}

// ---------------- assign: slot per (token,k) ----------------
__global__ __launch_bounds__(256) void assign_kernel(
    const int* __restrict__ expert_idx, const int* __restrict__ offsets,
    int* __restrict__ cursor, int* __restrict__ row_token, int* __restrict__ slot_of) {
  int i = blockIdx.x * 256 + threadIdx.x;   // [0, NROWS)
  int e = expert_idx[i];
  int pos = atomicAdd(&cursor[e], 1);
  int slot = offsets[e] + pos;
  row_token[slot] = i >> 1;
  slot_of[i] = slot;
}

// ---------------- gather + cast to bf16 ----------------
__global__ __launch_bounds__(256) void gather_kernel(
    const float* __restrict__ x, const int* __restrict__ row_token,
    uint16_t* __restrict__ xs) {
  int row = blockIdx.x;
  int tok = row_token[row];
  int c = threadIdx.x * 8;
  const float4* p = (const float4*)(x + (size_t)tok * H_DIM + c);
  float4 v0 = p[0], v1 = p[1];
  uint32_t p0 = (uint32_t)f2bf(v0.x) | ((uint32_t)f2bf(v0.y) << 16);
  uint32_t p1 = (uint32_t)f2bf(v0.z) | ((uint32_t)f2bf(v0.w) << 16);
  uint32_t p2 = (uint32_t)f2bf(v1.x) | ((uint32_t)f2bf(v1.y) << 16);
  uint32_t p3 = (uint32_t)f2bf(v1.z) | ((uint32_t)f2bf(v1.w) << 16);
  uint4 o; o.x = p0; o.y = p1; o.z = p2; o.w = p3;
  *(uint4*)(xs + (size_t)row * H_DIM + c) = o;
}

// ---------------- transpose+cast: [E][R][C] fp32 -> [E][C][R] bf16 ----------------
__global__ __launch_bounds__(256) void transpose_cast(
    const float* __restrict__ in, uint16_t* __restrict__ out, int R, int C) {
  __shared__ float tile[64][33];
  int e = blockIdx.z;
  int c0 = blockIdx.x * 32, r0 = blockIdx.y * 64;
  const float* src = in + (size_t)e * R * C;
  uint16_t* dst = out + (size_t)e * R * C;
  int tx = threadIdx.x, ty = threadIdx.y;   // (32, 8)
#pragma unroll
  for (int it = 0; it < 8; ++it) {
    int r = ty + it * 8;
    tile[r][tx] = src[(size_t)(r0 + r) * C + c0 + tx];
  }
  __syncthreads();
#pragma unroll
  for (int it = 0; it < 4; ++it) {
    int c = ty + it * 8;
    uint32_t lo = f2bf(tile[2 * tx][c]);
    uint32_t hi = f2bf(tile[2 * tx + 1][c]);
    *(uint32_t*)(dst + (size_t)(c0 + c) * R + r0 + 2 * tx) = lo | (hi << 16);
  }
}

// ---------------- async 16B global->LDS ----------------
__device__ __forceinline__ void gld16(const uint16_t* g, uint16_t* l) {
  __builtin_amdgcn_global_load_lds(
      (const __attribute__((address_space(1))) uint32_t*)(g),
      (__attribute__((address_space(3))) uint32_t*)(l), 16, 0, 0);
}

// ---------------- grouped GEMM, 256x256 tile, deep-pipelined (T2+T3+T4+T5) ----
// 512 threads = 8 waves (2M x 4N), wave tile 128x64. BK=64 split into two
// 32-k phases. LDS: 2 slots x {A_kh0,A_kh1,B_kh0,B_kh1} x 16KB = 128 KiB.
// Each 16KB sub-buffer keeps the proven layout: [256 rows][32 k] bf16,
// 4x16B segs/row, seg_phys = seg_log ^ ((row>>1)&3)  (measured 0 conflicts).
// Schedule per iter t (slot s=t&1):
//   P1: ds_read kstep0 frags(s); stage kh1(t+1)->s^1; vmcnt(8); bar;
//       lgkm(0)+schedbar; setprio(1); 32 MFMA; setprio(0); bar
//   P2: ds_read kstep1 frags(s); stage kh0(t+2)->s;   vmcnt(8); bar;
//       lgkm(0)+schedbar; setprio(1); 32 MFMA; setprio(0); bar
// vmcnt(8): 12 gld16 in flight max, each stage-group waited 3 phases after
// issue -> HBM latency fully covered; never drains to 0 in the loop.
template <int N, int K, bool GELU>
__global__ __launch_bounds__(512, 2) void gemm256(
    const uint16_t* __restrict__ A, const uint16_t* __restrict__ Bt,
    uint16_t* __restrict__ C,
    const int* __restrict__ tile_meta, const int* __restrict__ ntilesp) {
  int slot = blockIdx.y;
  if (slot >= *ntilesp) return;
  int row_start = tile_meta[slot * 4 + 0];
  int rows = tile_meta[slot * 4 + 1];
  int e = tile_meta[slot * 4 + 2];
  int n0 = blockIdx.x * 256;
  constexpr int KT = K / 64;

  extern __shared__ uint16_t smem[];   // 2 * 4 * 8192 uint16 = 128 KiB

  int tid = threadIdx.x;
  int lane = tid & 63;
  int wave = tid >> 6;
  int wr = wave >> 2;       // 0..1 -> row offset wr*128
  int wc = wave & 3;        // 0..3 -> col offset wc*64
  int lm = lane & 15;
  int lq = lane >> 4;

  f32x4 acc[8][4];
#pragma unroll
  for (int i = 0; i < 8; ++i)
#pragma unroll
    for (int j = 0; j < 4; ++j) acc[i][j] = (f32x4){0.f, 0.f, 0.f, 0.f};

  // staging chunk decode: per 16KB sub-buffer 1024 chunks of 16B,
  // thread handles chunks tid and tid+512. chunk c: row=c>>2, segP=c&3,
  // segL = segP ^ ((row>>1)&3). Note (row+128) keeps the same swizzle.
  int r0c = tid >> 2, sP0 = tid & 3;
  int r1c = r0c + 128;
  int sL0 = sP0 ^ ((r0c >> 1) & 3);     // == swizzle for r1c too
  int rac0 = r0c < rows ? r0c : rows - 1;
  int rac1 = r1c < rows ? r1c : rows - 1;
  const uint16_t* gA0 = A + (size_t)(row_start + rac0) * K + sL0 * 8;
  const uint16_t* gA1 = A + (size_t)(row_start + rac1) * K + sL0 * 8;
  const uint16_t* gB0 = Bt + ((size_t)e * N + n0 + r0c) * K + sL0 * 8;
  const uint16_t* gB1 = Bt + ((size_t)e * N + n0 + r1c) * K + sL0 * 8;

  auto stageA = [&](uint16_t* dst, int koff) {
    gld16(gA0 + koff, dst + tid * 8);
    gld16(gA1 + koff, dst + (tid + 512) * 8);
  };
  auto stageB = [&](uint16_t* dst, int koff) {
    gld16(gB0 + koff, dst + tid * 8);
    gld16(gB1 + koff, dst + (tid + 512) * 8);
  };

  // prologue: kh0(0),kh1(0) -> slot0 ; kh0(1) -> slot1   (12 gld16)
  stageA(smem + 0, 0);        stageB(smem + 16384, 0);
  stageA(smem + 8192, 32);    stageB(smem + 24576, 32);
  stageA(smem + 32768, 64);   stageB(smem + 49152, 64);
  asm volatile("s_waitcnt vmcnt(8)" ::: "memory");   // kh0(0) landed
  __builtin_amdgcn_s_barrier();

  bf16x8 af[8], bfr[4];
  for (int t = 0; t < KT; ++t) {
    int s = t & 1;
    uint16_t* Ls = smem + s * 32768;
    uint16_t* Lo = smem + (s ^ 1) * 32768;
    int kt1 = (t + 1 < KT) ? t + 1 : KT - 1;   // clamp: tail stages garbage
    int kt2 = (t + 2 < KT) ? t + 2 : KT - 1;   // into dead regions (uniform vmcnt)

    // ---- phase 1: kstep0 ----
#pragma unroll
    for (int mi = 0; mi < 8; ++mi) {
      int r = wr * 128 + mi * 16 + lm;
      af[mi] = *(const bf16x8*)(Ls + r * 32 + (lq ^ ((r >> 1) & 3)) * 8);
    }
#pragma unroll
    for (int ni = 0; ni < 4; ++ni) {
      int r = wc * 64 + ni * 16 + lm;
      bfr[ni] = *(const bf16x8*)(Ls + 16384 + r * 32 + (lq ^ ((r >> 1) & 3)) * 8);
    }
    stageA(Lo + 8192, kt1 * 64 + 32);    // kh1(t+1): region dead since t-1/P2
    stageB(Lo + 24576, kt1 * 64 + 32);
    asm volatile("s_waitcnt vmcnt(8)" ::: "memory");  // guarantees kh1(t) landed
    __builtin_amdgcn_s_barrier();
    asm volatile("s_waitcnt lgkmcnt(0)" ::: "memory");
    __builtin_amdgcn_sched_barrier(0);
    __builtin_amdgcn_s_setprio(1);
#pragma unroll
    for (int mi = 0; mi < 8; ++mi)
#pragma unroll
      for (int ni = 0; ni < 4; ++ni)
        acc[mi][ni] = __builtin_amdgcn_mfma_f32_16x16x32_bf16(af[mi], bfr[ni], acc[mi][ni], 0, 0, 0);
    __builtin_amdgcn_s_setprio(0);
    __builtin_amdgcn_s_barrier();

    // ---- phase 2: kstep1 ----
#pragma unroll
    for (int mi = 0; mi < 8; ++mi) {
      int r = wr * 128 + mi * 16 + lm;
      af[mi] = *(const bf16x8*)(Ls + 8192 + r * 32 + (lq ^ ((r >> 1) & 3)) * 8);
    }
#pragma unroll
    for (int ni = 0; ni < 4; ++ni) {
      int r = wc * 64 + ni * 16 + lm;
      bfr[ni] = *(const bf16x8*)(Ls + 24576 + r * 32 + (lq ^ ((r >> 1) & 3)) * 8);
    }
    stageA(Ls, kt2 * 64);                // kh0(t+2): region fully read in P1
    stageB(Ls + 16384, kt2 * 64);
    asm volatile("s_waitcnt vmcnt(8)" ::: "memory");  // guarantees kh0(t+1) landed
    __builtin_amdgcn_s_barrier();
    asm volatile("s_waitcnt lgkmcnt(0)" ::: "memory");
    __builtin_amdgcn_sched_barrier(0);
    __builtin_amdgcn_s_setprio(1);
#pragma unroll
    for (int mi = 0; mi < 8; ++mi)
#pragma unroll
      for (int ni = 0; ni < 4; ++ni)
        acc[mi][ni] = __builtin_amdgcn_mfma_f32_16x16x32_bf16(af[mi], bfr[ni], acc[mi][ni], 0, 0, 0);
    __builtin_amdgcn_s_setprio(0);
    __builtin_amdgcn_s_barrier();
  }
  asm volatile("s_waitcnt vmcnt(0)" ::: "memory");   // drain tail prefetches

  // epilogue: C/D layout col=lane&15, row=(lane>>4)*4+reg
#pragma unroll
  for (int mi = 0; mi < 8; ++mi) {
    int lrow = wr * 128 + mi * 16 + lq * 4;
#pragma unroll
    for (int r = 0; r < 4; ++r) {
      if (lrow + r < rows) {
        size_t base = (size_t)(row_start + lrow + r) * N + n0 + wc * 64;
#pragma unroll
        for (int ni = 0; ni < 4; ++ni) {
          float v = acc[mi][ni][r];
          if (GELU) v = gelu_tanh(v);
          C[base + ni * 16 + lm] = f2bf(v);
        }
      }
    }
  }
}

// ---------------- combine: y[t] = w0*out[slot0] + w1*out[slot1] ----------------
__global__ __launch_bounds__(256) void combine_kernel(
    const uint16_t* __restrict__ outb, const int* __restrict__ slot_of,
    const float* __restrict__ ew, float* __restrict__ y) {
  int t = blockIdx.x;
  int s0 = slot_of[2 * t], s1 = slot_of[2 * t + 1];
  float w0 = ew[2 * t], w1 = ew[2 * t + 1];
  int c = threadIdx.x * 8;
  uint4 a = *(const uint4*)(outb + (size_t)s0 * H_DIM + c);
  uint4 b = *(const uint4*)(outb + (size_t)s1 * H_DIM + c);
  float* yp = y + (size_t)t * H_DIM + c;
  float4 r0, r1;
  r0.x = w0 * bf2f(a.x & 0xffffu) + w1 * bf2f(b.x & 0xffffu);
  r0.y = w0 * bf2f(a.x >> 16)     + w1 * bf2f(b.x >> 16);
  r0.z = w0 * bf2f(a.y & 0xffffu) + w1 * bf2f(b.y & 0xffffu);
  r0.w = w0 * bf2f(a.y >> 16)     + w1 * bf2f(b.y >> 16);
  r1.x = w0 * bf2f(a.z & 0xffffu) + w1 * bf2f(b.z & 0xffffu);
  r1.y = w0 * bf2f(a.z >> 16)     + w1 * bf2f(b.z >> 16);
  r1.z = w0 * bf2f(a.w & 0xffffu) + w1 * bf2f(b.w & 0xffffu);
  r1.w = w0 * bf2f(a.w >> 16)     + w1 * bf2f(b.w >> 16);
  *(float4*)yp = r0;
  *(float4*)(yp + 4) = r1;
}

extern "C" void kernel_launch(void* const* d_in, const int* in_sizes, int n_in,
                              void* d_out, int out_size, void* d_ws, size_t ws_size,
                              hipStream_t stream) {
  const float* x  = (const float*)d_in[0];
  const float* rw = (const float*)d_in[1];
  const float* w1 = (const float*)d_in[2];
  const float* w2 = (const float*)d_in[3];
  float* y = (float*)d_out;
  float* out_counts = y + (size_t)T_TOK * H_DIM;   // 8 floats at the tail

  char* ws = (char*)d_ws;
  int* counts     = (int*)(ws + 0);
  int* cursor     = (int*)(ws + 64);
  int* ntilesp    = (int*)(ws + 128);
  int* offsets    = (int*)(ws + 192);
  int* tile_meta  = (int*)(ws + 1024);            // up to 72 tiles * 4 ints
  int* expert_idx = (int*)(ws + 8192);
  float* expert_w = (float*)(ws + 8192 + 65536);
  int* row_token  = (int*)(ws + 8192 + 2 * 65536);
  int* slot_of    = (int*)(ws + 8192 + 3 * 65536);
  const size_t MB = 1ull << 20;
  uint16_t* xs   = (uint16_t*)(ws + 1 * MB);      //  64 MB [NROWS][H]
  uint16_t* hbuf = (uint16_t*)(ws + 66 * MB);     // 128 MB [NROWS][I]
  uint16_t* outb = (uint16_t*)(ws + 194 * MB);    //  64 MB [NROWS][H]
  uint16_t* w1t  = (uint16_t*)(ws + 258 * MB);    // 128 MB [E][I][H]
  uint16_t* w2t  = (uint16_t*)(ws + 386 * MB);    // 128 MB [E][H][I]

  static bool attr_set = false;
  if (!attr_set) {
    attr_set = true;
    hipFuncSetAttribute(reinterpret_cast<const void*>(&gemm256<I_DIM, H_DIM, true>),
                        hipFuncAttributeMaxDynamicSharedMemorySize, 131072);
    hipFuncSetAttribute(reinterpret_cast<const void*>(&gemm256<H_DIM, I_DIM, false>),
                        hipFuncAttributeMaxDynamicSharedMemorySize, 131072);
  }

  hipMemsetAsync(d_ws, 0, 8192, stream);   // counters/cursors/meta zero

  router_kernel<<<T_TOK / 4, 256, 0, stream>>>(x, rw, expert_idx, expert_w, counts);
  plan_kernel<<<1, 64, 0, stream>>>(counts, offsets, tile_meta, ntilesp, out_counts);
  assign_kernel<<<NROWS / 256, 256, 0, stream>>>(expert_idx, offsets, cursor, row_token, slot_of);
  gather_kernel<<<NROWS, 256, 0, stream>>>(x, row_token, xs);
  transpose_cast<<<dim3(I_DIM / 32, H_DIM / 64, E_NUM), dim3(32, 8), 0, stream>>>(w1, w1t, H_DIM, I_DIM);
  transpose_cast<<<dim3(H_DIM / 32, I_DIM / 64, E_NUM), dim3(32, 8), 0, stream>>>(w2, w2t, I_DIM, H_DIM);
  gemm256<I_DIM, H_DIM, true>
      <<<dim3(I_DIM / 256, 72), 512, 131072, stream>>>(xs, w1t, hbuf, tile_meta, ntilesp);
  gemm256<H_DIM, I_DIM, false>
      <<<dim3(H_DIM / 256, 72), 512, 131072, stream>>>(hbuf, w2t, outb, tile_meta, ntilesp);
  combine_kernel<<<T_TOK, 256, 0, stream>>>(outb, slot_of, expert_w, y);
}